// Round 13
// baseline (162.356 us; speedup 1.0000x reference)
//
#include <hip/hip_runtime.h>
#include <stdint.h>

#define DDIM 1024
#define HH 16
#define HDIM 64
#define SS 2048

typedef short bf16x8 __attribute__((ext_vector_type(8)));
typedef float f32x4 __attribute__((ext_vector_type(4)));
typedef float f32x16 __attribute__((ext_vector_type(16)));
typedef unsigned short u16;

__device__ __forceinline__ unsigned f2bf(float f) {
  unsigned u = __builtin_bit_cast(unsigned, f);
  u = u + 0x7FFFu + ((u >> 16) & 1u);   // RNE (inputs finite)
  return u >> 16;
}

// packs RNE-converted a->lo16, b->hi16
__device__ __forceinline__ unsigned cvt_pk_bf16(float a, float b) {
  unsigned r;
  asm("v_cvt_pk_bf16_f32 %0, %1, %2" : "=v"(r) : "v"(a), "v"(b));
  return r;
}

// after: a = [a.l0_31 | b.l0_31], b = [a.l32_63 | b.l32_63]
__device__ __forceinline__ void pswap(unsigned& a, unsigned& b) {
  asm volatile("v_permlane32_swap_b32 %0, %1" : "+v"(a), "+v"(b));
}

__device__ __forceinline__ void gload16(const void* g, void* l) {
  __builtin_amdgcn_global_load_lds(
      (const __attribute__((address_space(1))) unsigned int*)g,
      (__attribute__((address_space(3))) unsigned int*)l, 16, 0, 0);
}

__device__ __forceinline__ f32x16 zero16() {
  f32x16 z;
#pragma unroll
  for (int r = 0; r < 16; r++) z[r] = 0.f;
  return z;
}

// ---------------- convert x: fp32 -> bf16 ----------------
__global__ void k_convert_x(const float* __restrict__ x, u16* __restrict__ xb) {
  int i = (blockIdx.x * 256 + threadIdx.x) * 4;
  float4 v = *(const float4*)(x + i);
  ushort4 o;
  o.x = (u16)f2bf(v.x); o.y = (u16)f2bf(v.y); o.z = (u16)f2bf(v.z); o.w = (u16)f2bf(v.w);
  *(ushort4*)(xb + i) = o;
}

// ---------------- transpose+convert weights: W[k][n] -> WT[n][k] bf16 ----------------
__global__ void k_transpose_w(const float* __restrict__ w0, const float* __restrict__ w1,
                              const float* __restrict__ w2, const float* __restrict__ w3,
                              u16* __restrict__ wt) {
  __shared__ float t[64][65];
  int z = blockIdx.z;
  const float* src = (z == 0) ? w0 : (z == 1) ? w1 : (z == 2) ? w2 : w3;
  u16* dst = wt + (size_t)z * DDIM * DDIM;
  int k0 = blockIdx.x * 64, n0 = blockIdx.y * 64;
  int tid = threadIdx.x;
  int c4 = tid & 15, rr = tid >> 4;
  for (int rep = 0; rep < 4; rep++) {
    int r = rr + rep * 16;
    float4 v = *(const float4*)(src + (size_t)(k0 + r) * DDIM + n0 + c4 * 4);
    t[r][c4 * 4 + 0] = v.x; t[r][c4 * 4 + 1] = v.y;
    t[r][c4 * 4 + 2] = v.z; t[r][c4 * 4 + 3] = v.w;
  }
  __syncthreads();
  for (int rep = 0; rep < 4; rep++) {
    int n = rr + rep * 16;
    ushort4 o;
    o.x = (u16)f2bf(t[c4 * 4 + 0][n]); o.y = (u16)f2bf(t[c4 * 4 + 1][n]);
    o.z = (u16)f2bf(t[c4 * 4 + 2][n]); o.w = (u16)f2bf(t[c4 * 4 + 3][n]);
    *(ushort4*)(dst + (size_t)(n0 + n) * DDIM + k0 + c4 * 4) = o;
  }
}

// ---------------- GEMM: tile 128x128, BK=64, K=1024; A[m][k], BT[n][k] bf16 ----------------
template <int MODE>
__global__ __launch_bounds__(256, 2) void k_gemm(const u16* __restrict__ A,
                                                 const u16* __restrict__ BT,
                                                 const float* __restrict__ bias,
                                                 void* __restrict__ O0,
                                                 void* __restrict__ O1,
                                                 void* __restrict__ O2) {
  __shared__ __align__(16) u16 lA[128 * 64];
  __shared__ __align__(16) u16 lB[128 * 64];
  const int tid = threadIdx.x;
  const int l = tid & 63, w = tid >> 6;
  const int wm = w >> 1, wn = w & 1;
  const int m0 = blockIdx.x * 128, n0 = blockIdx.y * 128;
  const int lr = l >> 4, lc = l & 15;

  const int srow = l >> 3;
  const int scol = ((l & 7) ^ srow) * 8;

  f32x4 acc[4][4];
  for (int mi = 0; mi < 4; mi++)
    for (int ni = 0; ni < 4; ni++)
      acc[mi][ni] = f32x4{0.f, 0.f, 0.f, 0.f};

  for (int kk = 0; kk < 16; kk++) {
    const int k0 = kk * 64;
    for (int i = 0; i < 4; i++) {
      int c = w * 4 + i;
      gload16(A + (size_t)(m0 + c * 8 + srow) * DDIM + k0 + scol, (char*)lA + c * 1024);
      gload16(BT + (size_t)(n0 + c * 8 + srow) * DDIM + k0 + scol, (char*)lB + c * 1024);
    }
    __syncthreads();
    for (int ks = 0; ks < 2; ks++) {
      bf16x8 af[4], bfr[4];
      for (int mi = 0; mi < 4; mi++) {
        int row = wm * 64 + mi * 16 + lc;
        int slot = (ks * 4 + lr) ^ (row & 7);
        af[mi] = *(const bf16x8*)((const char*)lA + row * 128 + slot * 16);
      }
      for (int ni = 0; ni < 4; ni++) {
        int row = wn * 64 + ni * 16 + lc;
        int slot = (ks * 4 + lr) ^ (row & 7);
        bfr[ni] = *(const bf16x8*)((const char*)lB + row * 128 + slot * 16);
      }
      for (int mi = 0; mi < 4; mi++)
        for (int ni = 0; ni < 4; ni++)
          acc[mi][ni] = __builtin_amdgcn_mfma_f32_16x16x32_bf16(af[mi], bfr[ni], acc[mi][ni], 0, 0, 0);
    }
    __syncthreads();
  }

  if (MODE == 0) {
    const int which = blockIdx.y >> 3;
    if (which == 0) {
      u16* C = (u16*)O0;
      const float c1 = 0.18033688011112043f;  // 0.125 * log2(e) folded into Q
      for (int mi = 0; mi < 4; mi++)
        for (int ni = 0; ni < 4; ni++) {
          int nl = (n0 + wn * 64 + ni * 16 + lc) & 1023;
          float badd = bias[nl];
          for (int r = 0; r < 4; r++) {
            int m = m0 + wm * 64 + mi * 16 + lr * 4 + r;
            C[(size_t)m * DDIM + nl] = (u16)f2bf((acc[mi][ni][r] + badd) * c1);
          }
        }
    } else if (which == 1) {
      u16* C = (u16*)O1;
      for (int mi = 0; mi < 4; mi++)
        for (int ni = 0; ni < 4; ni++) {
          int nl = (n0 + wn * 64 + ni * 16 + lc) & 1023;
          for (int r = 0; r < 4; r++) {
            int m = m0 + wm * 64 + mi * 16 + lr * 4 + r;
            C[(size_t)m * DDIM + nl] = (u16)f2bf(acc[mi][ni][r]);
          }
        }
    } else {
      u16* C = (u16*)O2;  // [bh][hd][s]
      for (int mi = 0; mi < 4; mi++)
        for (int ni = 0; ni < 4; ni++) {
          int nl = (n0 + wn * 64 + ni * 16 + lc) & 1023;
          int h = nl >> 6, hd = nl & 63;
          int m = m0 + wm * 64 + mi * 16 + lr * 4;
          int b = m >> 11, s = m & 2047;
          unsigned d0 = f2bf(acc[mi][ni][0]) | (f2bf(acc[mi][ni][1]) << 16);
          unsigned d1 = f2bf(acc[mi][ni][2]) | (f2bf(acc[mi][ni][3]) << 16);
          u16* p = C + ((size_t)((b * HH + h) * HDIM + hd)) * SS + s;
          *(unsigned*)(p) = d0;
          *(unsigned*)(p + 2) = d1;
        }
    }
  } else {
    float* C = (float*)O0;
    for (int mi = 0; mi < 4; mi++)
      for (int ni = 0; ni < 4; ni++) {
        int n = n0 + wn * 64 + ni * 16 + lc;
        float badd = bias[n];
        for (int r = 0; r < 4; r++) {
          int m = m0 + wm * 64 + mi * 16 + lr * 4 + r;
          C[(size_t)m * DDIM + n] = acc[mi][ni][r] + badd;
        }
      }
  }
}

// ---------------- flash attention: 32x32 in-register core + 128q blocks + split-K ----
// Block = 4 waves x 32 q = 128-q strip j (0..15); key chunk of <=8 tiles.
// 1280 blocks = exactly 5/CU, ALL resident (LDS 32KB x 5 = 160KB).
// Core = R10 (numerics-verified): in-register softmax, P via cvt_pk+permlane32_swap.
__global__ __launch_bounds__(256, 5) void k_attn(const u16* __restrict__ Q,
                                                 const u16* __restrict__ Kg,
                                                 const u16* __restrict__ Vt,
                                                 float* __restrict__ Opart,
                                                 float* __restrict__ Ml) {
  __shared__ __align__(16) u16 lK[2][64 * 64];  // [key][d] XOR-swizzled, dbuf (16 KB)
  __shared__ __align__(16) u16 lV[2][64 * 64];  // [hd][key] XOR-swizzled, dbuf (16 KB)

  const int tid = threadIdx.x;
  const int l = tid & 63, w = tid >> 6;          // 4 waves
  const int lq = l & 31, hi = l >> 5;
  // id = u*32 + bh: bh low bits (XCD affinity); u enumerates (j, chunk)
  const int id = blockIdx.x;
  const int bh = id & 31;
  int rem = id >> 5, j = 0;                      // chunks(j) = 1 + (j>>2)
  while (rem >= 1 + (j >> 2)) { rem -= 1 + (j >> 2); j++; }
  const int c = rem;
  const int b = bh >> 4, h = bh & 15;
  const int nkt_blk = 2 * j + 2;
  const int t0 = c * 8;
  const int t1 = min(t0 + 8, nkt_blk);           // tiles [t0, t1), size even >= 2
  const int nktw = 2 * j + 1 + (w >> 1);         // wave's active-tile count
  const int qglob = j * 128 + w * 32 + lq;

  const float slope2 = exp2f(-0.5f * (float)(h + 1)) * 1.4426950408889634f;
  const float sh4 = slope2 * (float)(4 * hi);

  // per-reg ALiBi constants: scr[r] = slope2 * crow(r) (crow = (r&3)+8*(r>>2))
  f32x16 scr;
#pragma unroll
  for (int r = 0; r < 16; r++) scr[r] = slope2 * (float)((r & 3) + 8 * (r >> 2));

  // Q B-frags: col q = lq, k(d) = sd*16 + hi*8 + jj
  bf16x8 qf[4];
#pragma unroll
  for (int sd = 0; sd < 4; sd++)
    qf[sd] = *(const bf16x8*)(Q + (size_t)(b * SS + qglob) * DDIM + h * HDIM + sd * 16 + hi * 8);

  f32x16 o0 = zero16(), o1 = zero16();
  float mrun = -3.0e38f, lrl = 0.f;

  const int srow = l >> 3;
  const int scol = ((l & 7) ^ srow) * 8;

  auto stage = [&](int kt, int bb) {
#pragma unroll
    for (int i = 0; i < 2; i++) {
      int cc = i * 4 + w;   // 8 chunks each (8 rows x 64 cols = 1 KB)
      gload16(Kg + (size_t)(b * SS + kt * 64 + cc * 8 + srow) * DDIM + h * HDIM + scol,
              (char*)lK[bb] + cc * 1024);
      gload16(Vt + ((size_t)bh * HDIM + cc * 8 + srow) * SS + kt * 64 + scol,
              (char*)lV[bb] + cc * 1024);
    }
  };

  // prologue: two tiles in flight (clamped; chunk size >= 2 always)
  stage(t0, 0);
  stage(t0 + 1 < t1 ? t0 + 1 : t1 - 1, 1);

  for (int t = t0; t < t1; t++) {
    asm volatile("s_waitcnt vmcnt(4)" ::: "memory");
    __builtin_amdgcn_s_barrier();
    asm volatile("" ::: "memory");
    if (t < nktw) {
      const char* Kc = (const char*)lK[t & 1];
      const char* Vc = (const char*)lV[t & 1];
      const bool lastp = (t == nktw - 1);
      const bool doT1 = !lastp || (w & 1);   // even wave's last tile: skip key-half 1
      const bool mT0 = lastp && !(w & 1);
      const bool mT1 = lastp && (w & 1);

      // S^T[key][q] = K . Q^T  (2 key-halves x 4 d-steps)
      f32x16 s0 = zero16(), s1 = zero16();
      __builtin_amdgcn_s_setprio(1);
#pragma unroll
      for (int sd = 0; sd < 4; sd++) {
        int row = lq;
        int slot = (2 * sd + hi) ^ (row & 7);
        bf16x8 a = *(const bf16x8*)(Kc + row * 128 + slot * 16);
        s0 = __builtin_amdgcn_mfma_f32_32x32x16_bf16(a, qf[sd], s0, 0, 0, 0);
      }
      if (doT1) {
#pragma unroll
        for (int sd = 0; sd < 4; sd++) {
          int row = 32 + lq;
          int slot = (2 * sd + hi) ^ (row & 7);
          bf16x8 a = *(const bf16x8*)(Kc + row * 128 + slot * 16);
          s1 = __builtin_amdgcn_mfma_f32_32x32x16_bf16(a, qf[sd], s1, 0, 0, 0);
        }
      }
      __builtin_amdgcn_s_setprio(0);

      // ALiBi (exp2 domain) + causal mask + per-lane max over held keys
      const float bt0 = -slope2 * (float)(t * 64) - sh4;
      const float bt1 = bt0 - slope2 * 32.f;
      float tmax = -3.0e38f;
#pragma unroll
      for (int r = 0; r < 16; r++) {
        float sv = (s0[r] + bt0) - scr[r];
        if (mT0) {
          int key = t * 64 + (r & 3) + 8 * (r >> 2) + 4 * hi;
          if (key > qglob) sv = -3.0e38f;
        }
        s0[r] = sv;
        tmax = fmaxf(tmax, sv);
      }
      if (doT1) {
#pragma unroll
        for (int r = 0; r < 16; r++) {
          float sv = (s1[r] + bt1) - scr[r];
          if (mT1) {
            int key = t * 64 + 32 + (r & 3) + 8 * (r >> 2) + 4 * hi;
            if (key > qglob) sv = -3.0e38f;
          }
          s1[r] = sv;
          tmax = fmaxf(tmax, sv);
        }
      }
      // column max: in-lane tree done; ONE cross-lane exchange (partner half)
      float tcol = fmaxf(tmax, __shfl_xor(tmax, 32));
      if (__any(tcol > mrun)) {
        float mnew = fmaxf(mrun, tcol);
        float corr = exp2f(mrun - mnew);
        lrl *= corr;
#pragma unroll
        for (int r = 0; r < 16; r++) { o0[r] *= corr; o1[r] *= corr; }
        mrun = mnew;
      }

      // p = exp2(sv - m): per-lane partial denominator (combined at epilogue)
      f32x4 ps = f32x4{0.f, 0.f, 0.f, 0.f};
#pragma unroll
      for (int r = 0; r < 16; r++) {
        float p = exp2f(s0[r] - mrun);
        s0[r] = p;
        ps[r & 3] += p;
      }
      if (doT1) {
#pragma unroll
        for (int r = 0; r < 16; r++) {
          float p = exp2f(s1[r] - mrun);
          s1[r] = p;
          ps[r & 3] += p;
        }
      }
      lrl += (ps[0] + ps[1]) + (ps[2] + ps[3]);

      // O^T[hd][q] += V^T . P : P -> B-frags in-register (cvt_pk + permlane32_swap)
      __builtin_amdgcn_s_setprio(1);
      auto pvstep = [&](const f32x16& cs, int s) {  // s = 16-key step 0..3 (unroll const)
        const int b8 = (s & 1) * 8;
        unsigned x1 = cvt_pk_bf16(cs[b8 + 0], cs[b8 + 1]);
        unsigned y1 = cvt_pk_bf16(cs[b8 + 4], cs[b8 + 5]);
        pswap(x1, y1);
        unsigned x2 = cvt_pk_bf16(cs[b8 + 2], cs[b8 + 3]);
        unsigned y2 = cvt_pk_bf16(cs[b8 + 6], cs[b8 + 7]);
        pswap(x2, y2);
        uint4 pw; pw.x = x1; pw.y = x2; pw.z = y1; pw.w = y2;
        bf16x8 pb = __builtin_bit_cast(bf16x8, pw);
        int slotb = 2 * s + hi;
        {
          int row = lq;
          bf16x8 va = *(const bf16x8*)(Vc + row * 128 + ((slotb ^ (row & 7)) << 4));
          o0 = __builtin_amdgcn_mfma_f32_32x32x16_bf16(va, pb, o0, 0, 0, 0);
        }
        {
          int row = 32 + lq;
          bf16x8 va = *(const bf16x8*)(Vc + row * 128 + ((slotb ^ (row & 7)) << 4));
          o1 = __builtin_amdgcn_mfma_f32_32x32x16_bf16(va, pb, o1, 0, 0, 0);
        }
      };
      pvstep(s0, 0);
      pvstep(s0, 1);
      if (doT1) {
        pvstep(s1, 2);
        pvstep(s1, 3);
      }
      __builtin_amdgcn_s_setprio(0);
    }
    __builtin_amdgcn_s_barrier();
    asm volatile("" ::: "memory");
    int kts = t + 2;
    if (kts > t1 - 1) kts = t1 - 1;   // redundant stage keeps vmcnt counts uniform
    stage(kts, t & 1);
  }

  // epilogue: combine per-lane denominator; write f32 partials + (m, l)
  float lcol = lrl + __shfl_xor(lrl, 32);
  float* Op = Opart + (size_t)id * 8192 + (w * 32 + lq) * 64;
#pragma unroll
  for (int rg = 0; rg < 4; rg++) {
    float4 v;
    v.x = o0[4 * rg + 0]; v.y = o0[4 * rg + 1]; v.z = o0[4 * rg + 2]; v.w = o0[4 * rg + 3];
    *(float4*)(Op + rg * 8 + 4 * hi) = v;
    v.x = o1[4 * rg + 0]; v.y = o1[4 * rg + 1]; v.z = o1[4 * rg + 2]; v.w = o1[4 * rg + 3];
    *(float4*)(Op + 32 + rg * 8 + 4 * hi) = v;
  }
  if (hi == 0) {
    float2 mlv; mlv.x = mrun; mlv.y = lcol;
    *(float2*)(Ml + (size_t)id * 256 + (w * 32 + lq) * 2) = mlv;
  }
}

// ---------------- combine partials: one block per (bh, qt64) ----------------
__global__ __launch_bounds__(256, 4) void k_combine(const float* __restrict__ Opart,
                                                    const float* __restrict__ Ml,
                                                    u16* __restrict__ AO) {
  const int blk = blockIdx.x;          // 1024 = qt*32 + bh (bh low -> XCD affinity)
  const int bh = blk & 31, qt = blk >> 5;
  const int b = bh >> 4, h = bh & 15;
  const int j = qt >> 1, g = j >> 2;
  const int nc = g + 1;                                  // chunks for strip j
  const int base = 2 * g * (g + 1) + (j & 3) * (g + 1);  // chunks before strip j
  const int tid = threadIdx.x;
  const int q = tid >> 2, seg = (tid & 3) << 4;          // 64 q x 4 segs of 16 hd
  const int q128 = (qt & 1) * 64 + q;                    // q within 128-strip

  float m0 = -3.0e38f, m1 = -3.0e38f, m2 = -3.0e38f, m3 = -3.0e38f;
  float l0 = 0.f, l1 = 0.f, l2 = 0.f, l3 = 0.f;
#pragma unroll 4
  for (int cc = 0; cc < 4; cc++) {
    if (cc >= nc) continue;
    int sid = (base + cc) * 32 + bh;
    float2 mlv = *(const float2*)(Ml + (size_t)sid * 256 + q128 * 2);
    if (cc == 0) { m0 = mlv.x; l0 = mlv.y; }
    else if (cc == 1) { m1 = mlv.x; l1 = mlv.y; }
    else if (cc == 2) { m2 = mlv.x; l2 = mlv.y; }
    else { m3 = mlv.x; l3 = mlv.y; }
  }
  float mstar = fmaxf(fmaxf(m0, m1), fmaxf(m2, m3));
  float s0 = exp2f(m0 - mstar), s1 = exp2f(m1 - mstar);
  float s2 = exp2f(m2 - mstar), s3 = exp2f(m3 - mstar);

  float acc[16];
#pragma unroll
  for (int r = 0; r < 16; r++) acc[r] = 0.f;
  float lstar = 0.f;
#pragma unroll 4
  for (int cc = 0; cc < 4; cc++) {
    if (cc >= nc) continue;
    float sc = (cc == 0) ? s0 : (cc == 1) ? s1 : (cc == 2) ? s2 : s3;
    lstar += ((cc == 0) ? l0 : (cc == 1) ? l1 : (cc == 2) ? l2 : l3) * sc;
    int sid = (base + cc) * 32 + bh;
    const float* Op = Opart + (size_t)sid * 8192 + q128 * 64 + seg;
#pragma unroll
    for (int r4 = 0; r4 < 4; r4++) {
      float4 v = *(const float4*)(Op + r4 * 4);
      acc[r4 * 4 + 0] += v.x * sc;
      acc[r4 * 4 + 1] += v.y * sc;
      acc[r4 * 4 + 2] += v.z * sc;
      acc[r4 * 4 + 3] += v.w * sc;
    }
  }
  float inv = 1.f / lstar;
  unsigned pk[8];
#pragma unroll
  for (int i = 0; i < 8; i++)
    pk[i] = f2bf(acc[2 * i] * inv) | (f2bf(acc[2 * i + 1] * inv) << 16);
  u16* ab = AO + (size_t)(b * SS + qt * 64 + q) * DDIM + h * HDIM + seg;
  uint4 w0; w0.x = pk[0]; w0.y = pk[1]; w0.z = pk[2]; w0.w = pk[3];
  uint4 w1; w1.x = pk[4]; w1.y = pk[5]; w1.z = pk[6]; w1.w = pk[7];
  *(uint4*)(ab) = w0;
  *(uint4*)(ab + 8) = w1;
}

extern "C" void kernel_launch(void* const* d_in, const int* in_sizes, int n_in,
                              void* d_out, int out_size, void* d_ws, size_t ws_size,
                              hipStream_t stream) {
  const float* x  = (const float*)d_in[0];
  const float* Wq = (const float*)d_in[1];
  const float* bq = (const float*)d_in[2];
  const float* Wk = (const float*)d_in[3];
  const float* Wv = (const float*)d_in[4];
  const float* Wo = (const float*)d_in[5];
  const float* bo = (const float*)d_in[6];
  float* out = (float*)d_out;

  u16* ws = (u16*)d_ws;
  const size_t MEG = 1024 * 1024;
  u16* xb = ws;                  // 4M elems
  u16* WT = ws + 4 * MEG;        // 4 x 1M elems: WqT,WkT,WvT,WoT
  u16* Qb = ws + 8 * MEG;        // 4M
  u16* Kb = ws + 12 * MEG;       // 4M
  u16* Vt = ws + 16 * MEG;       // 4M  [32][64][2048]
  u16* AO = ws + 20 * MEG;       // 4M
  float* Opart = (float*)(ws + 24 * MEG);          // 1280 x 8192 f32 = 41.9 MB
  float* Ml    = Opart + (size_t)1280 * 8192;      // 1280 x 256 f32 = 1.3 MB

  k_convert_x<<<dim3(4096), dim3(256), 0, stream>>>(x, xb);
  k_transpose_w<<<dim3(16, 16, 4), dim3(256), 0, stream>>>(Wq, Wk, Wv, Wo, WT);
  k_gemm<0><<<dim3(32, 24), dim3(256), 0, stream>>>(xb, WT, bq, (void*)Qb, (void*)Kb, (void*)Vt);
  k_attn<<<dim3(1280), dim3(256), 0, stream>>>(Qb, Kb, Vt, Opart, Ml);
  k_combine<<<dim3(1024), dim3(256), 0, stream>>>(Opart, Ml, AO);
  k_gemm<1><<<dim3(32, 8), dim3(256), 0, stream>>>(AO, WT + 3 * MEG, bo, (void*)out, nullptr, nullptr);
}